// Round 1
// baseline (484.026 us; speedup 1.0000x reference)
//
#include <hip/hip_runtime.h>
#include <hip/hip_bf16.h>
#include <math.h>

typedef __bf16 bf16_t;
typedef __bf16 bf16x4_t __attribute__((ext_vector_type(4)));
typedef __bf16 bf16x8_t __attribute__((ext_vector_type(8)));
typedef float  f32x4_t  __attribute__((ext_vector_type(4)));

#define N_TOK 4096
#define D_IN  4096
#define O_OUT 4096
#define NEXP  8
#define NHEAD 3
#define RANK  16
#define KC2   384      // E*H*R = 8*3*16
#define PCOLS 256      // padded projection cols (152 used: 128 A-cols + 24 R-cols)
#define SCALING_F 2.0f // lora_alpha/r = 32/16

// ---------------- conversion / packing kernels ----------------

// x fp32 [N,D] -> bf16 [N,D] (k-major for GEMM A-side)
__global__ void convert_x_kernel(const float* __restrict__ x, bf16_t* __restrict__ xb) {
  size_t i = (size_t)blockIdx.x * blockDim.x + threadIdx.x;  // grid sized exactly N*D/4
  float4 f = ((const float4*)x)[i];
  bf16x4_t o = { (bf16_t)f.x, (bf16_t)f.y, (bf16_t)f.z, (bf16_t)f.w };
  ((bf16x4_t*)xb)[i] = o;
}

// src fp32 [Rr,Cc] row-major -> dst bf16 [Cc,Rr] row-major (transpose+convert)
// 64x64 tiles via LDS, 256 threads. Both global read and write coalesced.
__global__ void transpose_cvt_kernel(const float* __restrict__ src, bf16_t* __restrict__ dst,
                                     int Rr, int Cc) {
  __shared__ float tile[64][65];  // +1 pad: conflict-free column reads
  int r0 = blockIdx.x * 64, c0 = blockIdx.y * 64;
  int tc = threadIdx.x & 63, tg = threadIdx.x >> 6;  // tg in 0..3
  #pragma unroll
  for (int k = tg; k < 64; k += 4)
    tile[k][tc] = src[(size_t)(r0 + k) * Cc + c0 + tc];
  __syncthreads();
  #pragma unroll
  for (int k = tg; k < 64; k += 4)
    dst[(size_t)(c0 + k) * Rr + r0 + tc] = (bf16_t)tile[tc][k];
}

// Pack A [E,D,R] and R [E,D,H] into PabT [PCOLS=256, D] bf16 (row c = projection col c,
// k-major). Rows 0..127: A col (e*16+r); 128..151: R col (e*3+h); 152..255: zero pad.
__global__ void pack_proj_kernel(const float* __restrict__ A, const float* __restrict__ Rm,
                                 bf16_t* __restrict__ PabT) {
  int c = blockIdx.x;  // 0..255
  for (int d = threadIdx.x; d < D_IN; d += 256) {
    float v = 0.f;
    if (c < 128) {
      int e = c >> 4, r = c & 15;
      v = A[((size_t)e * D_IN + d) * RANK + r];
    } else if (c < 152) {
      int q = c - 128; int e = q / 3, h = q - 3 * e;
      v = Rm[((size_t)e * D_IN + d) * NHEAD + h];
    }
    PabT[(size_t)c * D_IN + d] = (bf16_t)v;
  }
}

// ---------------- fp32 router: exact top-2 gate ----------------
// One wave per token. router_W is 128KB -> L2-resident across waves.
__global__ __launch_bounds__(256) void router_kernel(const float* __restrict__ x,
                                                     const float* __restrict__ rw,
                                                     int* __restrict__ gidx,
                                                     float* __restrict__ gwv) {
  int lane = threadIdx.x & 63;
  int wv = threadIdx.x >> 6;
  int n = blockIdx.x * 4 + wv;
  const float4* xv = (const float4*)(x + (size_t)n * D_IN);
  float acc[NEXP] = {0, 0, 0, 0, 0, 0, 0, 0};
  for (int d = lane; d < D_IN / 4; d += 64) {
    float4 xx = xv[d];
    #pragma unroll
    for (int e = 0; e < NEXP; ++e) {
      float4 ww = ((const float4*)(rw + (size_t)e * D_IN))[d];
      acc[e] += xx.x * ww.x + xx.y * ww.y + xx.z * ww.z + xx.w * ww.w;
    }
  }
  #pragma unroll
  for (int e = 0; e < NEXP; ++e) {
    float v = acc[e];
    #pragma unroll
    for (int o = 32; o > 0; o >>= 1) v += __shfl_down(v, o);
    acc[e] = v;  // full sum valid on lane 0
  }
  if (lane == 0) {
    int i0 = 0; float l0 = acc[0];
    #pragma unroll
    for (int e = 1; e < NEXP; ++e) if (acc[e] > l0) { l0 = acc[e]; i0 = e; }
    int i1 = -1; float l1 = -3.4e38f;
    #pragma unroll
    for (int e = 0; e < NEXP; ++e) if (e != i0 && acc[e] > l1) { l1 = acc[e]; i1 = e; }
    // renormalized top-2 softmax weights: w0 = e^l0/(e^l0+e^l1)
    float w0 = 1.f / (1.f + expf(l1 - l0));
    gidx[2 * n] = i0; gidx[2 * n + 1] = i1;
    gwv[2 * n] = w0;  gwv[2 * n + 1] = 1.f - w0;
  }
}

// ---------------- gating: build C2 [N, 384] bf16 ----------------
// C2[n, e*48+h*16+r] = SCALING * gate[n,e] * head_w[n,e,h] * a[n,e,r]; zero off top-2.
__global__ void gating_kernel(const float* __restrict__ proj, const int* __restrict__ gidx,
                              const float* __restrict__ gwv, bf16_t* __restrict__ C2b) {
  int n = blockIdx.x;
  int c = threadIdx.x;  // 0..383 (block = 384 = 6 waves)
  int e = c / 48;
  int h = (c % 48) / 16;
  int r = c & 15;
  int i0 = gidx[2 * n], i1 = gidx[2 * n + 1];
  float g = (e == i0) ? gwv[2 * n] : (e == i1) ? gwv[2 * n + 1] : 0.f;
  float val = 0.f;
  if (g != 0.f) {
    const float* pr = proj + (size_t)n * PCOLS;
    float h0 = pr[128 + e * 3 + 0];
    float h1 = pr[128 + e * 3 + 1];
    float h2 = pr[128 + e * 3 + 2];
    float mx = fmaxf(h0, fmaxf(h1, h2));
    float e0 = expf(h0 - mx), e1 = expf(h1 - mx), e2 = expf(h2 - mx);
    float hw = (h == 0 ? e0 : h == 1 ? e1 : e2) / (e0 + e1 + e2);
    val = SCALING_F * g * hw * pr[e * 16 + r];
  }
  C2b[(size_t)n * KC2 + c] = (bf16_t)val;
}

// ---------------- m97-style bf16 MFMA GEMM core ----------------
// C[128x128] (+= optional base) = A[128xK] * Bt[128xK]^T, BK=64.
// LDS tiles stored k-major in 16B chunks, XOR-swizzled: chunk(m,kc) at index m*8+(kc^(m&7)).
// Staging via global_load_lds width=16 (lane-contiguous LDS dests, swizzle folded into
// the per-lane GLOBAL address so LDS stays contiguous).

__device__ __forceinline__ void stage_tile(const bf16_t* __restrict__ gbase, int ld,
                                           bf16_t* sdst, int tid) {
  #pragma unroll
  for (int t = 0; t < 4; ++t) {
    int c = tid + t * 256;              // wave w covers chunks [w*64+t*256, +64): lane-contiguous
    int m = c >> 3;
    int kc = (c & 7) ^ (m & 7);         // XOR swizzle
    const bf16_t* g = gbase + (size_t)m * ld + kc * 8;
    __builtin_amdgcn_global_load_lds((const __attribute__((address_space(1))) void*)g,
                                     (__attribute__((address_space(3))) void*)(sdst + c * 8),
                                     16, 0, 0);
  }
}

__device__ __forceinline__ void gemm_block(bf16_t* sA, bf16_t* sB,
                                           const bf16_t* __restrict__ Ab, int lda,
                                           const bf16_t* __restrict__ Bb, int ldb,
                                           int K,
                                           float* __restrict__ Cb, int ldc,
                                           const float* __restrict__ addB) {
  const int tid = threadIdx.x;
  const int lane = tid & 63;
  const int w = tid >> 6;
  const int wm = (w >> 1) * 64;   // wave quadrant in 2x2 grid of 64x64
  const int wn = (w & 1) * 64;
  const int qd = lane >> 4;       // quad 0..3
  const int ln = lane & 15;

  f32x4_t acc[4][4] = {};

  for (int k0 = 0; k0 < K; k0 += 64) {
    __syncthreads();                       // prior-iter LDS reads done before overwrite
    stage_tile(Ab + k0, lda, sA, tid);
    stage_tile(Bb + k0, ldb, sB, tid);
    __syncthreads();                       // drains vmcnt for global_load_lds
    #pragma unroll
    for (int s = 0; s < 2; ++s) {          // two k-steps of 32 within BK=64
      bf16x8_t af[4], bfr[4];
      int kch = s * 4 + qd;                // 16B chunk within row
      #pragma unroll
      for (int i = 0; i < 4; ++i) {
        int m = wm + i * 16 + ln;          // A frag: A[m=lane&15][k=quad*8+j]
        af[i]  = *(const bf16x8_t*)(sA + ((m << 3) + (kch ^ (m & 7))) * 8);
        int n = wn + i * 16 + ln;          // B frag: Bt[n=lane&15][k=quad*8+j]
        bfr[i] = *(const bf16x8_t*)(sB + ((n << 3) + (kch ^ (n & 7))) * 8);
      }
      #pragma unroll
      for (int i = 0; i < 4; ++i)
        #pragma unroll
        for (int j = 0; j < 4; ++j)
          acc[i][j] = __builtin_amdgcn_mfma_f32_16x16x32_bf16(af[i], bfr[j], acc[i][j], 0, 0, 0);
    }
  }
  // epilogue: C/D layout col=lane&15, row=quad*4+reg (verified m89/m91)
  #pragma unroll
  for (int i = 0; i < 4; ++i) {
    #pragma unroll
    for (int j = 0; j < 4; ++j) {
      int col = wn + j * 16 + ln;
      #pragma unroll
      for (int rg = 0; rg < 4; ++rg) {
        int row = wm + i * 16 + qd * 4 + rg;
        size_t off = (size_t)row * ldc + col;
        float v = acc[i][j][rg];
        if (addB) v += addB[off];
        Cb[off] = v;
      }
    }
  }
}

// base GEMM fused with projection columns: out[4096,4096] = xb@WbT^T; proj[4096,256] = xb@PabT^T
__global__ __launch_bounds__(256) void gemm_base_kernel(const bf16_t* __restrict__ xb,
                                                        const bf16_t* __restrict__ WbT,
                                                        const bf16_t* __restrict__ PabT,
                                                        float* __restrict__ out,
                                                        float* __restrict__ proj) {
  __shared__ bf16_t sA[128 * 64];
  __shared__ bf16_t sB[128 * 64];
  int bm = blockIdx.x, bn = blockIdx.y;  // bn 0..33: 0..31 -> base W cols, 32..33 -> proj cols
  const bf16_t* Ab = xb + (size_t)bm * 128 * D_IN;
  const bf16_t* Bb;
  float* Cb; int ldc;
  if (bn < 32) {
    Bb  = WbT + (size_t)bn * 128 * D_IN;
    Cb  = out + (size_t)bm * 128 * O_OUT + bn * 128;
    ldc = O_OUT;
  } else {
    Bb  = PabT + (size_t)(bn - 32) * 128 * D_IN;
    Cb  = proj + (size_t)bm * 128 * PCOLS + (bn - 32) * 128;
    ldc = PCOLS;
  }
  gemm_block(sA, sB, Ab, D_IN, Bb, D_IN, D_IN, Cb, ldc, nullptr);
}

// delta GEMM: out += C2b[4096,384] @ BbT[4096,384]^T  (K=384 = 6 tiles)
__global__ __launch_bounds__(256) void gemm_delta_kernel(const bf16_t* __restrict__ C2b,
                                                         const bf16_t* __restrict__ BbT,
                                                         float* __restrict__ out) {
  __shared__ bf16_t sA[128 * 64];
  __shared__ bf16_t sB[128 * 64];
  int bm = blockIdx.x, bn = blockIdx.y;
  const bf16_t* Ab = C2b + (size_t)bm * 128 * KC2;
  const bf16_t* Bb = BbT + (size_t)bn * 128 * KC2;
  float* Cb = out + (size_t)bm * 128 * O_OUT + bn * 128;
  gemm_block(sA, sB, Ab, KC2, Bb, KC2, KC2, Cb, O_OUT, Cb);
}

// ---------------- launch ----------------
// ws layout (bytes):
//   xb    @ 0         : 33554432  (bf16 [4096,4096])
//   WbT   @ 33554432  : 33554432  (bf16 [4096,4096], base_W transposed)
//   PabT  @ 67108864  : 2097152   (bf16 [256,4096])
//   BbT   @ 69206016  : 3145728   (bf16 [4096,384], Bflat transposed)
//   proj  @ 72351744  : 4194304   (f32 [4096,256])
//   C2b   @ 76546048  : 3145728   (bf16 [4096,384])
//   gidx  @ 79691776  : 32768     (int [4096,2])
//   gwv   @ 79724544  : 32768     (f32 [4096,2])
extern "C" void kernel_launch(void* const* d_in, const int* in_sizes, int n_in,
                              void* d_out, int out_size, void* d_ws, size_t ws_size,
                              hipStream_t stream) {
  const float* x       = (const float*)d_in[0];
  const float* base_W  = (const float*)d_in[1];
  const float* routerW = (const float*)d_in[2];
  const float* A       = (const float*)d_in[3];
  const float* B       = (const float*)d_in[4];
  const float* Rm      = (const float*)d_in[5];
  float* out = (float*)d_out;
  char* ws = (char*)d_ws;

  bf16_t* xb   = (bf16_t*)(ws);
  bf16_t* WbT  = (bf16_t*)(ws + 33554432);
  bf16_t* PabT = (bf16_t*)(ws + 67108864);
  bf16_t* BbT  = (bf16_t*)(ws + 69206016);
  float*  proj = (float*) (ws + 72351744);
  bf16_t* C2b  = (bf16_t*)(ws + 76546048);
  int*    gidx = (int*)   (ws + 79691776);
  float*  gwv  = (float*) (ws + 79724544);

  // conversions / packing (independent; stream-serialized is fine)
  convert_x_kernel<<<16384, 256, 0, stream>>>(x, xb);
  transpose_cvt_kernel<<<dim3(64, 64), 256, 0, stream>>>(base_W, WbT, 4096, 4096);
  transpose_cvt_kernel<<<dim3(6, 64), 256, 0, stream>>>(B, BbT, KC2, 4096);  // Bflat [384,4096] -> [4096,384]
  pack_proj_kernel<<<256, 256, 0, stream>>>(A, Rm, PabT);
  router_kernel<<<1024, 256, 0, stream>>>(x, routerW, gidx, gwv);

  // big fused GEMM: base output + lora-A / head-router projections
  gemm_base_kernel<<<dim3(32, 34), 256, 0, stream>>>(xb, WbT, PabT, out, proj);

  // per-token gating -> C2
  gating_kernel<<<4096, 384, 0, stream>>>(proj, gidx, gwv, C2b);

  // delta GEMM accumulating into out
  gemm_delta_kernel<<<dim3(32, 32), 256, 0, stream>>>(C2b, BbT, out);
}

// Round 2
// 429.953 us; speedup vs baseline: 1.1258x; 1.1258x over previous
//
#include <hip/hip_runtime.h>
#include <hip/hip_bf16.h>
#include <math.h>

typedef __bf16 bf16_t;
typedef __bf16 bf16x4_t __attribute__((ext_vector_type(4)));
typedef __bf16 bf16x8_t __attribute__((ext_vector_type(8)));
typedef float  f32x4_t  __attribute__((ext_vector_type(4)));

#define N_TOK 4096
#define D_IN  4096
#define O_OUT 4096
#define NEXP  8
#define NHEAD 3
#define RANK  16
#define KC2   384      // E*H*R = 8*3*16
#define PCOLS 256      // padded projection cols (152 used: 128 A-cols + 24 R-cols)
#define SCALING_F 2.0f // lora_alpha/r = 32/16

// ---------------- fused convert + fp32 router ----------------
// One wave per token: reads x (fp32) ONCE, writes xb (bf16) and exact top-2 gates.
__global__ __launch_bounds__(256) void cvt_router_kernel(const float* __restrict__ x,
                                                         const float* __restrict__ rw,
                                                         bf16_t* __restrict__ xb,
                                                         int* __restrict__ gidx,
                                                         float* __restrict__ gwv) {
  int lane = threadIdx.x & 63;
  int wv = threadIdx.x >> 6;
  int n = blockIdx.x * 4 + wv;
  const float4* xv = (const float4*)(x + (size_t)n * D_IN);
  bf16x4_t* xo = (bf16x4_t*)(xb + (size_t)n * D_IN);
  float acc[NEXP] = {0, 0, 0, 0, 0, 0, 0, 0};
  for (int d = lane; d < D_IN / 4; d += 64) {
    float4 xx = xv[d];
    bf16x4_t ob = { (bf16_t)xx.x, (bf16_t)xx.y, (bf16_t)xx.z, (bf16_t)xx.w };
    xo[d] = ob;
    #pragma unroll
    for (int e = 0; e < NEXP; ++e) {
      float4 ww = ((const float4*)(rw + (size_t)e * D_IN))[d];
      acc[e] += xx.x * ww.x + xx.y * ww.y + xx.z * ww.z + xx.w * ww.w;
    }
  }
  #pragma unroll
  for (int e = 0; e < NEXP; ++e) {
    float v = acc[e];
    #pragma unroll
    for (int o = 32; o > 0; o >>= 1) v += __shfl_down(v, o);
    acc[e] = v;
  }
  if (lane == 0) {
    int i0 = 0; float l0 = acc[0];
    #pragma unroll
    for (int e = 1; e < NEXP; ++e) if (acc[e] > l0) { l0 = acc[e]; i0 = e; }
    int i1 = -1; float l1 = -3.4e38f;
    #pragma unroll
    for (int e = 0; e < NEXP; ++e) if (e != i0 && acc[e] > l1) { l1 = acc[e]; i1 = e; }
    float w0 = 1.f / (1.f + expf(l1 - l0));
    gidx[2 * n] = i0; gidx[2 * n + 1] = i1;
    gwv[2 * n] = w0;  gwv[2 * n + 1] = 1.f - w0;
  }
}

// ---------------- vectorized transpose + fp32->bf16 ----------------
// src fp32 [Rr,Cc] -> dst bf16 [Cc,Rr]. 64x64 tiles, float4 loads, bf16x4 stores,
// LDS access pattern 2-way max (free on gfx950).
__global__ __launch_bounds__(256) void transpose_cvt_kernel(const float* __restrict__ src,
                                                            bf16_t* __restrict__ dst,
                                                            int Rr, int Cc) {
  __shared__ float tile[64][65];
  int r0 = blockIdx.x * 64, c0 = blockIdx.y * 64;
  int q  = threadIdx.x & 15;   // col-quad 0..15
  int r4 = threadIdx.x >> 4;   // 0..15
  #pragma unroll
  for (int g = 0; g < 4; ++g) {
    int r = r4 + g * 16;
    float4 v = *(const float4*)(src + (size_t)(r0 + r) * Cc + c0 + q * 4);
    tile[r][q * 4 + 0] = v.x; tile[r][q * 4 + 1] = v.y;
    tile[r][q * 4 + 2] = v.z; tile[r][q * 4 + 3] = v.w;
  }
  __syncthreads();
  #pragma unroll
  for (int g = 0; g < 4; ++g) {
    int c = r4 + g * 16;  // output row (source column)
    bf16x4_t o = { (bf16_t)tile[q * 4 + 0][c], (bf16_t)tile[q * 4 + 1][c],
                   (bf16_t)tile[q * 4 + 2][c], (bf16_t)tile[q * 4 + 3][c] };
    *(bf16x4_t*)(dst + (size_t)(c0 + c) * Rr + r0 + q * 4) = o;
  }
}

// Pack A [E,D,R] and R [E,D,H] into PabT [PCOLS=256, D] bf16 (k-major).
// Rows 0..127: A col (e*16+r); 128..151: R col (e*3+h); 152..255: zero.
__global__ void pack_proj_kernel(const float* __restrict__ A, const float* __restrict__ Rm,
                                 bf16_t* __restrict__ PabT) {
  int c = blockIdx.x;
  for (int d = threadIdx.x; d < D_IN; d += 256) {
    float v = 0.f;
    if (c < 128) {
      int e = c >> 4, r = c & 15;
      v = A[((size_t)e * D_IN + d) * RANK + r];
    } else if (c < 152) {
      int qq = c - 128; int e = qq / 3, h = qq - 3 * e;
      v = Rm[((size_t)e * D_IN + d) * NHEAD + h];
    }
    PabT[(size_t)c * D_IN + d] = (bf16_t)v;
  }
}

// ---------------- gating: build C2 [N, 384] bf16 ----------------
__global__ void gating_kernel(const float* __restrict__ proj, const int* __restrict__ gidx,
                              const float* __restrict__ gwv, bf16_t* __restrict__ C2b) {
  int n = blockIdx.x;
  int c = threadIdx.x;  // 0..383
  int e = c / 48;
  int h = (c % 48) / 16;
  int r = c & 15;
  int i0 = gidx[2 * n], i1 = gidx[2 * n + 1];
  float g = (e == i0) ? gwv[2 * n] : (e == i1) ? gwv[2 * n + 1] : 0.f;
  float val = 0.f;
  if (g != 0.f) {
    const float* pr = proj + (size_t)n * PCOLS;
    float h0 = pr[128 + e * 3 + 0];
    float h1 = pr[128 + e * 3 + 1];
    float h2 = pr[128 + e * 3 + 2];
    float mx = fmaxf(h0, fmaxf(h1, h2));
    float e0 = expf(h0 - mx), e1 = expf(h1 - mx), e2 = expf(h2 - mx);
    float hw = (h == 0 ? e0 : h == 1 ? e1 : e2) / (e0 + e1 + e2);
    val = SCALING_F * g * hw * pr[e * 16 + r];
  }
  C2b[(size_t)n * KC2 + c] = (bf16_t)val;
}

// ---------------- m97-style MFMA K-loop core ----------------
// 128x128 tile, BK=64, XOR-swizzled LDS (0 bank conflicts verified), width-16
// global_load_lds staging. Per-thread staging offsets hoisted (k0-additive).
__device__ __forceinline__ void run_kloop(f32x4_t (&acc)[4][4], bf16_t* sA, bf16_t* sB,
                                          const bf16_t* __restrict__ Ab, int lda,
                                          const bf16_t* __restrict__ Bb, int ldb, int K) {
  const int tid = threadIdx.x;
  const int lane = tid & 63;
  const int w = tid >> 6;
  const int wm = (w >> 1) * 64;
  const int wn = (w & 1) * 64;
  const int qd = lane >> 4;
  const int ln = lane & 15;
  const int sw = ln & 7;  // m&7 == ln&7 for all fragment rows (wm,16*i are mults of 8)

  size_t offA[4], offB[4];
  int lo[4];
  #pragma unroll
  for (int t = 0; t < 4; ++t) {
    int c = tid + t * 256;
    int m = c >> 3, kc = (c & 7) ^ (m & 7);
    offA[t] = (size_t)m * lda + kc * 8;
    offB[t] = (size_t)m * ldb + kc * 8;
    lo[t] = c * 8;
  }
  int rowA[4], rowB[4];
  #pragma unroll
  for (int i = 0; i < 4; ++i) {
    rowA[i] = (wm + i * 16 + ln) * 64;
    rowB[i] = (wn + i * 16 + ln) * 64;
  }

  for (int k0 = 0; k0 < K; k0 += 64) {
    __syncthreads();
    #pragma unroll
    for (int t = 0; t < 4; ++t)
      __builtin_amdgcn_global_load_lds(
          (const __attribute__((address_space(1))) void*)(Ab + k0 + offA[t]),
          (__attribute__((address_space(3))) void*)(sA + lo[t]), 16, 0, 0);
    #pragma unroll
    for (int t = 0; t < 4; ++t)
      __builtin_amdgcn_global_load_lds(
          (const __attribute__((address_space(1))) void*)(Bb + k0 + offB[t]),
          (__attribute__((address_space(3))) void*)(sB + lo[t]), 16, 0, 0);
    __syncthreads();
    #pragma unroll
    for (int s = 0; s < 2; ++s) {
      bf16x8_t af[4], bfr[4];
      int kx = ((s * 4 + qd) ^ sw) * 8;
      #pragma unroll
      for (int i = 0; i < 4; ++i) af[i]  = *(const bf16x8_t*)(sA + rowA[i] + kx);
      #pragma unroll
      for (int i = 0; i < 4; ++i) bfr[i] = *(const bf16x8_t*)(sB + rowB[i] + kx);
      #pragma unroll
      for (int i = 0; i < 4; ++i)
        #pragma unroll
        for (int j = 0; j < 4; ++j)
          acc[i][j] = __builtin_amdgcn_mfma_f32_16x16x32_bf16(af[i], bfr[j], acc[i][j], 0, 0, 0);
    }
  }
}

// proj split-K GEMM: proj[4096,256] += xb[bm rows] @ PabT^T (K slice of 1024), atomicAdd.
__global__ __launch_bounds__(256) void gemm_proj_kernel(const bf16_t* __restrict__ xb,
                                                        const bf16_t* __restrict__ PabT,
                                                        float* __restrict__ proj) {
  __shared__ bf16_t sA[128 * 64];
  __shared__ bf16_t sB[128 * 64];
  int bm = blockIdx.x, bn = blockIdx.y, kz = blockIdx.z;
  f32x4_t acc[4][4] = {};
  run_kloop(acc, sA, sB,
            xb + (size_t)bm * 128 * D_IN + kz * 1024, D_IN,
            PabT + (size_t)bn * 128 * D_IN + kz * 1024, D_IN, 1024);
  const int lane = threadIdx.x & 63, w = threadIdx.x >> 6;
  const int wm = (w >> 1) * 64, wn = (w & 1) * 64, qd = lane >> 4, ln = lane & 15;
  float* Cb = proj + (size_t)bm * 128 * PCOLS + bn * 128;
  #pragma unroll
  for (int i = 0; i < 4; ++i)
    #pragma unroll
    for (int j = 0; j < 4; ++j) {
      int col = wn + j * 16 + ln;
      #pragma unroll
      for (int rg = 0; rg < 4; ++rg) {
        int row = wm + i * 16 + qd * 4 + rg;
        atomicAdd(&Cb[(size_t)row * PCOLS + col], acc[i][j][rg]);
      }
    }
}

// fused big GEMM: out = xb@WbT^T (K=4096) + C2b@BbT^T (K=384), one epilogue write.
__global__ __launch_bounds__(256) void gemm_fused_kernel(const bf16_t* __restrict__ xb,
                                                         const bf16_t* __restrict__ WbT,
                                                         const bf16_t* __restrict__ C2b,
                                                         const bf16_t* __restrict__ BbT,
                                                         float* __restrict__ out) {
  __shared__ bf16_t sA[128 * 64];
  __shared__ bf16_t sB[128 * 64];
  int bm = blockIdx.x, bn = blockIdx.y;
  f32x4_t acc[4][4] = {};
  run_kloop(acc, sA, sB,
            xb + (size_t)bm * 128 * D_IN, D_IN,
            WbT + (size_t)bn * 128 * D_IN, D_IN, D_IN);
  run_kloop(acc, sA, sB,
            C2b + (size_t)bm * 128 * KC2, KC2,
            BbT + (size_t)bn * 128 * KC2, KC2, KC2);
  const int lane = threadIdx.x & 63, w = threadIdx.x >> 6;
  const int wm = (w >> 1) * 64, wn = (w & 1) * 64, qd = lane >> 4, ln = lane & 15;
  float* Cb = out + (size_t)bm * 128 * O_OUT + bn * 128;
  #pragma unroll
  for (int i = 0; i < 4; ++i)
    #pragma unroll
    for (int j = 0; j < 4; ++j) {
      int col = wn + j * 16 + ln;
      #pragma unroll
      for (int rg = 0; rg < 4; ++rg) {
        int row = wm + i * 16 + qd * 4 + rg;
        Cb[(size_t)row * O_OUT + col] = acc[i][j][rg];
      }
    }
}

// ---------------- launch ----------------
// ws layout (bytes):
//   xb    @ 0         : 33554432  (bf16 [4096,4096])
//   WbT   @ 33554432  : 33554432  (bf16 [4096,4096])
//   PabT  @ 67108864  : 2097152   (bf16 [256,4096])
//   BbT   @ 69206016  : 3145728   (bf16 [4096,384])
//   proj  @ 72351744  : 4194304   (f32 [4096,256])
//   C2b   @ 76546048  : 3145728   (bf16 [4096,384])
//   gidx  @ 79691776  : 32768     (int [4096,2])
//   gwv   @ 79724544  : 32768     (f32 [4096,2])
extern "C" void kernel_launch(void* const* d_in, const int* in_sizes, int n_in,
                              void* d_out, int out_size, void* d_ws, size_t ws_size,
                              hipStream_t stream) {
  const float* x       = (const float*)d_in[0];
  const float* base_W  = (const float*)d_in[1];
  const float* routerW = (const float*)d_in[2];
  const float* A       = (const float*)d_in[3];
  const float* B       = (const float*)d_in[4];
  const float* Rm      = (const float*)d_in[5];
  float* out = (float*)d_out;
  char* ws = (char*)d_ws;

  bf16_t* xb   = (bf16_t*)(ws);
  bf16_t* WbT  = (bf16_t*)(ws + 33554432);
  bf16_t* PabT = (bf16_t*)(ws + 67108864);
  bf16_t* BbT  = (bf16_t*)(ws + 69206016);
  float*  proj = (float*) (ws + 72351744);
  bf16_t* C2b  = (bf16_t*)(ws + 76546048);
  int*    gidx = (int*)   (ws + 79691776);
  float*  gwv  = (float*) (ws + 79724544);

  // zero proj accumulator (split-K atomics land here)
  hipMemsetAsync(proj, 0, (size_t)N_TOK * PCOLS * sizeof(float), stream);

  // prefix: conversions / packing / router
  cvt_router_kernel<<<1024, 256, 0, stream>>>(x, routerW, xb, gidx, gwv);
  transpose_cvt_kernel<<<dim3(64, 64), 256, 0, stream>>>(base_W, WbT, 4096, 4096);
  transpose_cvt_kernel<<<dim3(6, 64), 256, 0, stream>>>(B, BbT, KC2, 4096);
  pack_proj_kernel<<<256, 256, 0, stream>>>(A, Rm, PabT);

  // proj GEMM (split-K=4) -> gating -> C2
  gemm_proj_kernel<<<dim3(32, 2, 4), 256, 0, stream>>>(xb, PabT, proj);
  gating_kernel<<<4096, 384, 0, stream>>>(proj, gidx, gwv, C2b);

  // single big GEMM: base + delta fused, clean 32x32 grid, single out write
  gemm_fused_kernel<<<dim3(32, 32), 256, 0, stream>>>(xb, WbT, C2b, BbT, out);
}

// Round 3
// 414.918 us; speedup vs baseline: 1.1666x; 1.0362x over previous
//
#include <hip/hip_runtime.h>
#include <hip/hip_bf16.h>
#include <math.h>

typedef __bf16 bf16_t;
typedef __bf16 bf16x4_t __attribute__((ext_vector_type(4)));
typedef __bf16 bf16x8_t __attribute__((ext_vector_type(8)));
typedef float  f32x4_t  __attribute__((ext_vector_type(4)));

#define N_TOK 4096
#define D_IN  4096
#define O_OUT 4096
#define NEXP  8
#define NHEAD 3
#define RANK  16
#define KC2   384      // E*H*R
#define PCOLS 256      // padded projection cols (152 used)
#define SCALING_F 2.0f

// ---------------- prep building blocks ----------------

// 64x64 transpose tile fp32 -> bf16, vectorized, <=2-way LDS aliasing (free).
__device__ __forceinline__ void transpose_tile(const float* __restrict__ src,
                                               bf16_t* __restrict__ dst,
                                               int Rr, int Cc, int r0, int c0,
                                               float (*tile)[65]) {
  int q  = threadIdx.x & 15;
  int r4 = threadIdx.x >> 4;
  #pragma unroll
  for (int g = 0; g < 4; ++g) {
    int r = r4 + g * 16;
    float4 v = *(const float4*)(src + (size_t)(r0 + r) * Cc + c0 + q * 4);
    tile[r][q * 4 + 0] = v.x; tile[r][q * 4 + 1] = v.y;
    tile[r][q * 4 + 2] = v.z; tile[r][q * 4 + 3] = v.w;
  }
  __syncthreads();
  #pragma unroll
  for (int g = 0; g < 4; ++g) {
    int c = r4 + g * 16;
    bf16x4_t o = { (bf16_t)tile[q * 4 + 0][c], (bf16_t)tile[q * 4 + 1][c],
                   (bf16_t)tile[q * 4 + 2][c], (bf16_t)tile[q * 4 + 3][c] };
    *(bf16x4_t*)(dst + (size_t)(c0 + c) * Rr + r0 + q * 4) = o;
  }
}

// ---------------- ONE prep kernel: all independent pre-GEMM work ----------------
// blocks [0,4096):    transpose+cvt base_W [4096,4096] -> WbT
// blocks [4096,5120): convert x->bf16 fused with exact fp32 top-2 router (4 tok/blk)
// blocks [5120,5504): transpose+cvt Bflat [384,4096] -> BbT
// blocks [5504,5760): pack A/R columns -> PabT [256,4096] k-major
__global__ __launch_bounds__(256) void prep_kernel(const float* __restrict__ x,
                                                   const float* __restrict__ base_W,
                                                   const float* __restrict__ rw,
                                                   const float* __restrict__ A,
                                                   const float* __restrict__ B,
                                                   const float* __restrict__ Rm,
                                                   bf16_t* __restrict__ xb,
                                                   bf16_t* __restrict__ WbT,
                                                   bf16_t* __restrict__ BbT,
                                                   bf16_t* __restrict__ PabT,
                                                   int* __restrict__ gidx,
                                                   float* __restrict__ gwv) {
  __shared__ float tile[64][65];
  int b = blockIdx.x;
  if (b < 4096) {
    transpose_tile(base_W, WbT, 4096, 4096, (b & 63) * 64, (b >> 6) * 64, tile);
  } else if (b < 5120) {
    int lane = threadIdx.x & 63;
    int wv = threadIdx.x >> 6;
    int n = (b - 4096) * 4 + wv;
    const float4* xv = (const float4*)(x + (size_t)n * D_IN);
    bf16x4_t* xo = (bf16x4_t*)(xb + (size_t)n * D_IN);
    float acc[NEXP] = {0, 0, 0, 0, 0, 0, 0, 0};
    for (int d = lane; d < D_IN / 4; d += 64) {
      float4 xx = xv[d];
      bf16x4_t ob = { (bf16_t)xx.x, (bf16_t)xx.y, (bf16_t)xx.z, (bf16_t)xx.w };
      xo[d] = ob;
      #pragma unroll
      for (int e = 0; e < NEXP; ++e) {
        float4 ww = ((const float4*)(rw + (size_t)e * D_IN))[d];
        acc[e] += xx.x * ww.x + xx.y * ww.y + xx.z * ww.z + xx.w * ww.w;
      }
    }
    #pragma unroll
    for (int e = 0; e < NEXP; ++e) {
      float v = acc[e];
      #pragma unroll
      for (int o = 32; o > 0; o >>= 1) v += __shfl_down(v, o);
      acc[e] = v;
    }
    if (lane == 0) {
      int i0 = 0; float l0 = acc[0];
      #pragma unroll
      for (int e = 1; e < NEXP; ++e) if (acc[e] > l0) { l0 = acc[e]; i0 = e; }
      int i1 = -1; float l1 = -3.4e38f;
      #pragma unroll
      for (int e = 0; e < NEXP; ++e) if (e != i0 && acc[e] > l1) { l1 = acc[e]; i1 = e; }
      float w0 = 1.f / (1.f + expf(l1 - l0));
      gidx[2 * n] = i0; gidx[2 * n + 1] = i1;
      gwv[2 * n] = w0;  gwv[2 * n + 1] = 1.f - w0;
    }
  } else if (b < 5504) {
    int t = b - 5120;
    transpose_tile(B, BbT, KC2, 4096, (t % 6) * 64, (t / 6) * 64, tile);
  } else {
    int c = b - 5504;  // 0..255: output row of PabT
    for (int d = threadIdx.x; d < D_IN; d += 256) {
      float v = 0.f;
      if (c < 128) {
        int e = c >> 4, r = c & 15;
        v = A[((size_t)e * D_IN + d) * RANK + r];
      } else if (c < 152) {
        int qq = c - 128; int e = qq / 3, h = qq - 3 * e;
        v = Rm[((size_t)e * D_IN + d) * NHEAD + h];
      }
      PabT[(size_t)c * D_IN + d] = (bf16_t)v;
    }
  }
}

// ---------------- gating: C2[n, e*48+h*16+r], summing 4 split-K partials ----------------
__global__ void gating_kernel(const float* __restrict__ projP, const int* __restrict__ gidx,
                              const float* __restrict__ gwv, bf16_t* __restrict__ C2b) {
  int n = blockIdx.x;
  int c = threadIdx.x;  // 0..383
  int e = c / 48;
  int h = (c % 48) / 16;
  int r = c & 15;
  int i0 = gidx[2 * n], i1 = gidx[2 * n + 1];
  float g = (e == i0) ? gwv[2 * n] : (e == i1) ? gwv[2 * n + 1] : 0.f;
  float val = 0.f;
  if (g != 0.f) {
    const float* p0 = projP + (size_t)n * PCOLS;
    const size_t S = (size_t)N_TOK * PCOLS;
    #define RD(cc) (p0[(cc)] + p0[(cc) + S] + p0[(cc) + 2 * S] + p0[(cc) + 3 * S])
    float h0 = RD(128 + e * 3 + 0);
    float h1 = RD(128 + e * 3 + 1);
    float h2 = RD(128 + e * 3 + 2);
    float av = RD(e * 16 + r);
    #undef RD
    float mx = fmaxf(h0, fmaxf(h1, h2));
    float e0 = expf(h0 - mx), e1 = expf(h1 - mx), e2 = expf(h2 - mx);
    float hw = (h == 0 ? e0 : h == 1 ? e1 : e2) / (e0 + e1 + e2);
    val = SCALING_F * g * hw * av;
  }
  C2b[(size_t)n * KC2 + c] = (bf16_t)val;
}

// ---------------- m97-style MFMA K-loop core (unchanged: 0 conflicts verified) ----------------
__device__ __forceinline__ void run_kloop(f32x4_t (&acc)[4][4], bf16_t* sA, bf16_t* sB,
                                          const bf16_t* __restrict__ Ab, int lda,
                                          const bf16_t* __restrict__ Bb, int ldb, int K) {
  const int tid = threadIdx.x;
  const int lane = tid & 63;
  const int w = tid >> 6;
  const int wm = (w >> 1) * 64;
  const int wn = (w & 1) * 64;
  const int qd = lane >> 4;
  const int ln = lane & 15;
  const int sw = ln & 7;

  size_t offA[4], offB[4];
  int lo[4];
  #pragma unroll
  for (int t = 0; t < 4; ++t) {
    int c = tid + t * 256;
    int m = c >> 3, kc = (c & 7) ^ (m & 7);
    offA[t] = (size_t)m * lda + kc * 8;
    offB[t] = (size_t)m * ldb + kc * 8;
    lo[t] = c * 8;
  }
  int rowA[4], rowB[4];
  #pragma unroll
  for (int i = 0; i < 4; ++i) {
    rowA[i] = (wm + i * 16 + ln) * 64;
    rowB[i] = (wn + i * 16 + ln) * 64;
  }

  for (int k0 = 0; k0 < K; k0 += 64) {
    __syncthreads();
    #pragma unroll
    for (int t = 0; t < 4; ++t)
      __builtin_amdgcn_global_load_lds(
          (const __attribute__((address_space(1))) void*)(Ab + k0 + offA[t]),
          (__attribute__((address_space(3))) void*)(sA + lo[t]), 16, 0, 0);
    #pragma unroll
    for (int t = 0; t < 4; ++t)
      __builtin_amdgcn_global_load_lds(
          (const __attribute__((address_space(1))) void*)(Bb + k0 + offB[t]),
          (__attribute__((address_space(3))) void*)(sB + lo[t]), 16, 0, 0);
    __syncthreads();
    #pragma unroll
    for (int s = 0; s < 2; ++s) {
      bf16x8_t af[4], bfr[4];
      int kx = ((s * 4 + qd) ^ sw) * 8;
      #pragma unroll
      for (int i = 0; i < 4; ++i) af[i]  = *(const bf16x8_t*)(sA + rowA[i] + kx);
      #pragma unroll
      for (int i = 0; i < 4; ++i) bfr[i] = *(const bf16x8_t*)(sB + rowB[i] + kx);
      #pragma unroll
      for (int i = 0; i < 4; ++i)
        #pragma unroll
        for (int j = 0; j < 4; ++j)
          acc[i][j] = __builtin_amdgcn_mfma_f32_16x16x32_bf16(af[i], bfr[j], acc[i][j], 0, 0, 0);
    }
  }
}

// proj split-K GEMM: projP[kz][4096,256] = xb @ PabT^T partial (K slice 1024), plain stores.
__global__ __launch_bounds__(256) void gemm_proj_kernel(const bf16_t* __restrict__ xb,
                                                        const bf16_t* __restrict__ PabT,
                                                        float* __restrict__ projP) {
  __shared__ bf16_t sA[128 * 64];
  __shared__ bf16_t sB[128 * 64];
  int bm = blockIdx.x, bn = blockIdx.y, kz = blockIdx.z;
  f32x4_t acc[4][4] = {};
  run_kloop(acc, sA, sB,
            xb + (size_t)bm * 128 * D_IN + kz * 1024, D_IN,
            PabT + (size_t)bn * 128 * D_IN + kz * 1024, D_IN, 1024);
  const int lane = threadIdx.x & 63, w = threadIdx.x >> 6;
  const int wm = (w >> 1) * 64, wn = (w & 1) * 64, qd = lane >> 4, ln = lane & 15;
  float* Cb = projP + (size_t)kz * N_TOK * PCOLS + (size_t)bm * 128 * PCOLS + bn * 128;
  #pragma unroll
  for (int i = 0; i < 4; ++i)
    #pragma unroll
    for (int j = 0; j < 4; ++j) {
      int col = wn + j * 16 + ln;
      #pragma unroll
      for (int rg = 0; rg < 4; ++rg) {
        int row = wm + i * 16 + qd * 4 + rg;
        Cb[(size_t)row * PCOLS + col] = acc[i][j][rg];
      }
    }
}

// fused big GEMM: out = xb@WbT^T (K=4096) + C2b@BbT^T (K=384), single epilogue write.
__global__ __launch_bounds__(256) void gemm_fused_kernel(const bf16_t* __restrict__ xb,
                                                         const bf16_t* __restrict__ WbT,
                                                         const bf16_t* __restrict__ C2b,
                                                         const bf16_t* __restrict__ BbT,
                                                         float* __restrict__ out) {
  __shared__ bf16_t sA[128 * 64];
  __shared__ bf16_t sB[128 * 64];
  int bm = blockIdx.x, bn = blockIdx.y;
  f32x4_t acc[4][4] = {};
  run_kloop(acc, sA, sB,
            xb + (size_t)bm * 128 * D_IN, D_IN,
            WbT + (size_t)bn * 128 * D_IN, D_IN, D_IN);
  run_kloop(acc, sA, sB,
            C2b + (size_t)bm * 128 * KC2, KC2,
            BbT + (size_t)bn * 128 * KC2, KC2, KC2);
  const int lane = threadIdx.x & 63, w = threadIdx.x >> 6;
  const int wm = (w >> 1) * 64, wn = (w & 1) * 64, qd = lane >> 4, ln = lane & 15;
  float* Cb = out + (size_t)bm * 128 * O_OUT + bn * 128;
  #pragma unroll
  for (int i = 0; i < 4; ++i)
    #pragma unroll
    for (int j = 0; j < 4; ++j) {
      int col = wn + j * 16 + ln;
      #pragma unroll
      for (int rg = 0; rg < 4; ++rg) {
        int row = wm + i * 16 + qd * 4 + rg;
        Cb[(size_t)row * O_OUT + col] = acc[i][j][rg];
      }
    }
}

// ---------------- launch ----------------
// ws layout (bytes):
//   xb    @ 0         : 33554432  (bf16 [4096,4096])
//   WbT   @ 33554432  : 33554432  (bf16 [4096,4096])
//   PabT  @ 67108864  : 2097152   (bf16 [256,4096])
//   BbT   @ 69206016  : 3145728   (bf16 [4096,384])
//   C2b   @ 72351744  : 3145728   (bf16 [4096,384])
//   gidx  @ 75497472  : 32768
//   gwv   @ 75530240  : 32768
// projP [4][4096][256] fp32 (16 MB) lives in d_out (dead until final GEMM overwrites).
extern "C" void kernel_launch(void* const* d_in, const int* in_sizes, int n_in,
                              void* d_out, int out_size, void* d_ws, size_t ws_size,
                              hipStream_t stream) {
  const float* x       = (const float*)d_in[0];
  const float* base_W  = (const float*)d_in[1];
  const float* routerW = (const float*)d_in[2];
  const float* A       = (const float*)d_in[3];
  const float* B       = (const float*)d_in[4];
  const float* Rm      = (const float*)d_in[5];
  float* out = (float*)d_out;
  char* ws = (char*)d_ws;

  bf16_t* xb   = (bf16_t*)(ws);
  bf16_t* WbT  = (bf16_t*)(ws + 33554432);
  bf16_t* PabT = (bf16_t*)(ws + 67108864);
  bf16_t* BbT  = (bf16_t*)(ws + 69206016);
  bf16_t* C2b  = (bf16_t*)(ws + 72351744);
  int*    gidx = (int*)   (ws + 75497472);
  float*  gwv  = (float*) (ws + 75530240);
  float*  projP = out;  // scratch: fully dead before gemm_fused writes out

  // 1) all independent prep in one saturating launch
  prep_kernel<<<5760, 256, 0, stream>>>(x, base_W, routerW, A, B, Rm,
                                        xb, WbT, BbT, PabT, gidx, gwv);
  // 2) proj split-K GEMM (non-atomic partials into d_out scratch)
  gemm_proj_kernel<<<dim3(32, 2, 4), 256, 0, stream>>>(xb, PabT, projP);
  // 3) gating -> C2 (sums 4 partials)
  gating_kernel<<<4096, 384, 0, stream>>>(projP, gidx, gwv, C2b);
  // 4) fused base+delta GEMM, single out write
  gemm_fused_kernel<<<dim3(32, 32), 256, 0, stream>>>(xb, WbT, C2b, BbT, out);
}